// Round 1
// baseline (605.425 us; speedup 1.0000x reference)
//
#include <hip/hip_runtime.h>

// Problem constants (match reference): B=64, T=2048, H=256, A=4.
// Reference collapses: w_avg[b,t,a] = (t==0 ? 0 : 1) exactly (se_excl>0 for
// all t>=1 since exp(a-amax) >= exp(-~5), no underflow possible for this
// input distribution). So out[b,t,h*A+a] = X[b,t,h] * (t>0).
// Pure memory op: 128 MiB read + 512 MiB write.

#define NB 64
#define NT 2048
#define NH 256
#define NA 4

__global__ __launch_bounds__(256) void attn_bcast_kernel(
    const float* __restrict__ X,   // [B*T*H]
    float4* __restrict__ out,      // [B*T*H] float4s (A=4 splat)
    int n)                         // n = B*T*H
{
    int i = blockIdx.x * blockDim.x + threadIdx.x;
    if (i >= n) return;
    float v = X[i];
    // t = (i / H) % T ; H=256 -> >>8 ; T=2048 -> &2047
    if ((((unsigned)i >> 8) & 2047u) == 0u) v = 0.0f;  // zero the t==0 slice
    out[i] = make_float4(v, v, v, v);
}

extern "C" void kernel_launch(void* const* d_in, const int* in_sizes, int n_in,
                              void* d_out, int out_size, void* d_ws, size_t ws_size,
                              hipStream_t stream) {
    const float* X = (const float*)d_in[0];  // [B, T, H] float32
    // d_in[1..4] = W1, b1, W2, b2 — unused: the reference's softmax-prefix
    // weighting is exactly the indicator (t>0), independent of a's values.
    float4* out4 = (float4*)d_out;           // [B, T, H*A] viewed as [B*T*H] float4

    const int n = NB * NT * NH;              // 33,554,432 (divisible by 256)
    dim3 grid(n / 256), block(256);
    attn_bcast_kernel<<<grid, block, 0, stream>>>(X, out4, n);
}